// Round 2
// baseline (389.450 us; speedup 1.0000x reference)
//
#include <hip/hip_runtime.h>

#define SQ 4096
#define DD 64
#define NB 4
#define NEL (NB*SQ*DD)   // 1,048,576 elements per tensor

typedef __attribute__((ext_vector_type(4))) float f32x4;
typedef __attribute__((ext_vector_type(8))) __bf16 bf16x8;

__device__ __forceinline__ unsigned short f2bf(float f) {
  unsigned int u = __builtin_bit_cast(unsigned int, f);
  u = (u + 0x7FFFu + ((u >> 16) & 1u)) >> 16;   // RNE
  return (unsigned short)u;
}

__device__ __forceinline__ bf16x8 ldfrag(const unsigned short* p) {
  uint4 u = *(const uint4*)p;
  return __builtin_bit_cast(bf16x8, u);
}

// ---------------- prep: Q,K -> bf16 ; V -> bf16 transposed [D][S] ----------------
__global__ __launch_bounds__(256) void prep_kernel(
    const float* __restrict__ q, const float* __restrict__ k,
    const float* __restrict__ v, unsigned short* __restrict__ ws)
{
  unsigned short* qbf = ws;
  unsigned short* kbf = ws + (size_t)NEL;
  unsigned short* vt  = ws + 2*(size_t)NEL;
  const int bid = blockIdx.x;
  const int tid = threadIdx.x;
  if (bid < 1024) {
    // 512 blocks for Q, 512 for K; each converts 512 float4s
    const float* src = (bid < 512) ? q : k;
    unsigned short* dst = (bid < 512) ? qbf : kbf;
    const int base = (bid & 511) * 512 + tid;
#pragma unroll
    for (int i = 0; i < 2; ++i) {
      int idx = base + i * 256;
      float4 f = ((const float4*)src)[idx];
      ushort4 o;
      o.x = f2bf(f.x); o.y = f2bf(f.y); o.z = f2bf(f.z); o.w = f2bf(f.w);
      ((ushort4*)dst)[idx] = o;
    }
  } else {
    // transpose V: one block per (batch, 64-row s-tile)
    __shared__ unsigned short tile[64][66];
    const int t  = bid - 1024;
    const int bb = t >> 6;
    const int st = t & 63;
    const float* vb = v + (size_t)bb * SQ * DD + (size_t)st * 64 * DD;
    const int r  = tid >> 4;   // 0..15
    const int c4 = tid & 15;   // 0..15
#pragma unroll
    for (int j = 0; j < 4; ++j) {
      int row = r + j * 16;
      float4 f = ((const float4*)(vb + (size_t)row * DD))[c4];
      tile[row][c4 * 4 + 0] = f2bf(f.x);
      tile[row][c4 * 4 + 1] = f2bf(f.y);
      tile[row][c4 * 4 + 2] = f2bf(f.z);
      tile[row][c4 * 4 + 3] = f2bf(f.w);
    }
    __syncthreads();
    unsigned short* vtb = vt + (size_t)bb * DD * SQ;
#pragma unroll
    for (int j = 0; j < 4; ++j) {
      int d   = r + j * 16;
      int s0l = c4 * 4;
      ushort4 o;
      o.x = tile[s0l + 0][d];
      o.y = tile[s0l + 1][d];
      o.z = tile[s0l + 2][d];
      o.w = tile[s0l + 3][d];
      ((ushort4*)(vtb + (size_t)d * SQ + st * 64))[c4] = o;
    }
  }
}

// ---------------- main fused attention ----------------
// grid: 512 blocks (b = idx&3, qt = 127 - idx>>2  -> heavy tiles dispatched first)
// block: 128 threads = 2 waves; wave w owns q rows [qt*32 + w*16, +16)
__global__ __launch_bounds__(128) void attn_kernel(
    const unsigned short* __restrict__ qbf,
    const unsigned short* __restrict__ kbf,
    const unsigned short* __restrict__ vtp,
    float* __restrict__ out_vec,
    float* __restrict__ out_w)
{
  __shared__ __align__(16) unsigned short pw[2][16][72];  // P transpose staging, per-wave

  const int tid  = threadIdx.x;
  const int wave = tid >> 6;
  const int lane = tid & 63;
  const int l16  = lane & 15;
  const int quad = lane >> 4;

  const int bidx = blockIdx.x;
  const int b    = bidx & 3;
  const int qt   = 127 - (bidx >> 2);

  const unsigned short* Qb = qbf + (size_t)b * SQ * DD;
  const unsigned short* Kb = kbf + (size_t)b * SQ * DD;
  const unsigned short* Vt = vtp + (size_t)b * DD * SQ;  // [D][S]
  float* Wb = out_w  + (size_t)b * SQ * SQ;
  float* Ob = out_vec + (size_t)b * SQ * DD;

  const int q0    = qt * 32 + wave * 16;
  const int rowg0 = q0 + quad * 4;           // + r

  // A fragments of Q (rows q0+l16, k = quad*8 + j [+32])
  bf16x8 aQ0, aQ1;
  {
    const unsigned short* qrow = Qb + (size_t)(q0 + l16) * DD + quad * 8;
    aQ0 = ldfrag(qrow);
    aQ1 = ldfrag(qrow + 32);
  }

  const int nkt = (qt * 32 + 31) / 64 + 1;   // causal k-tiles of 64
  const float SC = 0.125f * 1.4426950408889634f;  // 1/sqrt(D) * log2(e)
  const f32x4 zf = {0.f, 0.f, 0.f, 0.f};

  // ---- phase 1: softmax denominators (no max-subtraction; logits2 <= ~8.3) ----
  float lsum[4] = {0.f, 0.f, 0.f, 0.f};
  for (int kt = 0; kt < nkt; ++kt) {
    const int k0 = kt * 64;
    f32x4 acc[4] = {zf, zf, zf, zf};
#pragma unroll
    for (int ct = 0; ct < 4; ++ct) {
      const unsigned short* krow = Kb + (size_t)(k0 + ct * 16 + l16) * DD + quad * 8;
      bf16x8 b0 = ldfrag(krow);
      bf16x8 b1 = ldfrag(krow + 32);
      acc[ct] = __builtin_amdgcn_mfma_f32_16x16x32_bf16(aQ0, b0, acc[ct], 0, 0, 0);
      acc[ct] = __builtin_amdgcn_mfma_f32_16x16x32_bf16(aQ1, b1, acc[ct], 0, 0, 0);
    }
#pragma unroll
    for (int ct = 0; ct < 4; ++ct) {
      const int colg = k0 + ct * 16 + l16;
#pragma unroll
      for (int r = 0; r < 4; ++r) {
        float tt = (colg <= rowg0 + r) ? acc[ct][r] * SC : -1e30f;
        lsum[r] += __builtin_amdgcn_exp2f(tt);
      }
    }
  }
  float inv_l[4];
#pragma unroll
  for (int r = 0; r < 4; ++r) {
    float vsum = lsum[r];
    vsum += __shfl_xor(vsum, 1);
    vsum += __shfl_xor(vsum, 2);
    vsum += __shfl_xor(vsum, 4);
    vsum += __shfl_xor(vsum, 8);
    inv_l[r] = 1.0f / vsum;
  }

  // ---- phase 2: recompute scores, write P, accumulate O = P*V ----
  f32x4 accO[4] = {zf, zf, zf, zf};
  for (int kt = 0; kt < nkt; ++kt) {
    const int k0 = kt * 64;
    f32x4 acc[4] = {zf, zf, zf, zf};
#pragma unroll
    for (int ct = 0; ct < 4; ++ct) {
      const unsigned short* krow = Kb + (size_t)(k0 + ct * 16 + l16) * DD + quad * 8;
      bf16x8 b0 = ldfrag(krow);
      bf16x8 b1 = ldfrag(krow + 32);
      acc[ct] = __builtin_amdgcn_mfma_f32_16x16x32_bf16(aQ0, b0, acc[ct], 0, 0, 0);
      acc[ct] = __builtin_amdgcn_mfma_f32_16x16x32_bf16(aQ1, b1, acc[ct], 0, 0, 0);
    }
#pragma unroll
    for (int ct = 0; ct < 4; ++ct) {
      const int colg = k0 + ct * 16 + l16;
#pragma unroll
      for (int r = 0; r < 4; ++r) {
        float tt = (colg <= rowg0 + r) ? acc[ct][r] * SC : -1e30f;
        float p  = __builtin_amdgcn_exp2f(tt) * inv_l[r];
        __builtin_nontemporal_store(p, Wb + (size_t)(rowg0 + r) * SQ + colg);
        pw[wave][quad * 4 + r][ct * 16 + l16] = f2bf(p);
      }
    }
    __syncthreads();   // cross-lane LDS write -> read
    bf16x8 aP0 = ldfrag(&pw[wave][l16][quad * 8]);
    bf16x8 aP1 = ldfrag(&pw[wave][l16][32 + quad * 8]);
#pragma unroll
    for (int ct = 0; ct < 4; ++ct) {
      const unsigned short* vrow = Vt + (size_t)(ct * 16 + l16) * SQ + k0 + quad * 8;
      bf16x8 b0 = ldfrag(vrow);
      bf16x8 b1 = ldfrag(vrow + 32);
      accO[ct] = __builtin_amdgcn_mfma_f32_16x16x32_bf16(aP0, b0, accO[ct], 0, 0, 0);
      accO[ct] = __builtin_amdgcn_mfma_f32_16x16x32_bf16(aP1, b1, accO[ct], 0, 0, 0);
    }
    __syncthreads();   // protect pw reads from next-iter writes
  }

  // ---- epilogue: write attn_vec ----
#pragma unroll
  for (int ct = 0; ct < 4; ++ct)
#pragma unroll
    for (int r = 0; r < 4; ++r)
      Ob[(size_t)(rowg0 + r) * DD + ct * 16 + l16] = accO[ct][r];

  // ---- zero-fill the fully-masked columns [nkt*64, S) for all 32 rows ----
  const int zc0 = nkt * 64;
  const int nz4 = (SQ - zc0) >> 2;
  if (nz4 > 0) {
    const f32x4 z = {0.f, 0.f, 0.f, 0.f};
    for (int r = 0; r < 32; ++r) {
      f32x4* zp = (f32x4*)(Wb + (size_t)(qt * 32 + r) * SQ + zc0);
      for (int i = tid; i < nz4; i += 128)
        __builtin_nontemporal_store(z, zp + i);
    }
  }
}

extern "C" void kernel_launch(void* const* d_in, const int* in_sizes, int n_in,
                              void* d_out, int out_size, void* d_ws, size_t ws_size,
                              hipStream_t stream) {
  const float* q = (const float*)d_in[0];
  const float* k = (const float*)d_in[1];
  const float* v = (const float*)d_in[2];
  float* out_vec = (float*)d_out;
  float* out_w   = out_vec + (size_t)NB * SQ * DD;
  unsigned short* ws = (unsigned short*)d_ws;  // needs 3*NEL*2 = 6 MB

  hipLaunchKernelGGL(prep_kernel, dim3(1280), dim3(256), 0, stream, q, k, v, ws);
  hipLaunchKernelGGL(attn_kernel, dim3(512), dim3(128), 0, stream,
                     ws, ws + (size_t)NEL, ws + 2 * (size_t)NEL, out_vec, out_w);
}

// Round 3
// 351.508 us; speedup vs baseline: 1.1079x; 1.1079x over previous
//
#include <hip/hip_runtime.h>

#define SQ 4096
#define DD 64
#define NB 4
#define NEL (NB*SQ*DD)   // 1,048,576 elements per tensor

typedef __attribute__((ext_vector_type(4))) float f32x4;
typedef __attribute__((ext_vector_type(8))) __bf16 bf16x8;

__device__ __forceinline__ unsigned short f2bf(float f) {
  unsigned int u = __builtin_bit_cast(unsigned int, f);
  u = (u + 0x7FFFu + ((u >> 16) & 1u)) >> 16;   // RNE
  return (unsigned short)u;
}

__device__ __forceinline__ bf16x8 ldfrag(const unsigned short* p) {
  uint4 u = *(const uint4*)p;
  return __builtin_bit_cast(bf16x8, u);
}

// ---------------- prep: Q,K -> bf16 ; V -> bf16 transposed [D][S] ----------------
__global__ __launch_bounds__(256) void prep_kernel(
    const float* __restrict__ q, const float* __restrict__ k,
    const float* __restrict__ v, unsigned short* __restrict__ ws)
{
  unsigned short* qbf = ws;
  unsigned short* kbf = ws + (size_t)NEL;
  unsigned short* vt  = ws + 2*(size_t)NEL;
  const int bid = blockIdx.x;
  const int tid = threadIdx.x;
  if (bid < 1024) {
    const float* src = (bid < 512) ? q : k;
    unsigned short* dst = (bid < 512) ? qbf : kbf;
    const int base = (bid & 511) * 512 + tid;
#pragma unroll
    for (int i = 0; i < 2; ++i) {
      int idx = base + i * 256;
      float4 f = ((const float4*)src)[idx];
      ushort4 o;
      o.x = f2bf(f.x); o.y = f2bf(f.y); o.z = f2bf(f.z); o.w = f2bf(f.w);
      ((ushort4*)dst)[idx] = o;
    }
  } else {
    // transpose V: one block per (batch, 64-row s-tile)
    __shared__ unsigned short tile[64][66];
    const int t  = bid - 1024;
    const int bb = t >> 6;
    const int st = t & 63;
    const float* vb = v + (size_t)bb * SQ * DD + (size_t)st * 64 * DD;
    const int r  = tid >> 4;
    const int c4 = tid & 15;
#pragma unroll
    for (int j = 0; j < 4; ++j) {
      int row = r + j * 16;
      float4 f = ((const float4*)(vb + (size_t)row * DD))[c4];
      tile[row][c4 * 4 + 0] = f2bf(f.x);
      tile[row][c4 * 4 + 1] = f2bf(f.y);
      tile[row][c4 * 4 + 2] = f2bf(f.z);
      tile[row][c4 * 4 + 3] = f2bf(f.w);
    }
    __syncthreads();
    unsigned short* vtb = vt + (size_t)bb * DD * SQ;
#pragma unroll
    for (int j = 0; j < 4; ++j) {
      int d   = r + j * 16;
      int s0l = c4 * 4;
      ushort4 o;
      o.x = tile[s0l + 0][d];
      o.y = tile[s0l + 1][d];
      o.z = tile[s0l + 2][d];
      o.w = tile[s0l + 3][d];
      ((ushort4*)(vtb + (size_t)d * SQ + st * 64))[c4] = o;
    }
  }
}

// ---------------- main fused attention ----------------
// grid: 1024 blocks; b = idx&3, qt = 255 - idx>>2 (heavy q-tiles first, 16 rows each)
// block: 256 threads = 4 waves; ALL waves share the same 16 q-rows, k-tiles are
// split wave-interleaved (wave w takes kt = w, w+4, ...). No barriers in the
// k-loops: P-transpose staging is per-wave (intra-wave LDS ordering via lgkmcnt).
__global__ __launch_bounds__(256, 4) void attn_kernel(
    const unsigned short* __restrict__ qbf,
    const unsigned short* __restrict__ kbf,
    const unsigned short* __restrict__ vtp,
    float* __restrict__ out_vec,
    float* __restrict__ out_w)
{
  __shared__ __align__(16) unsigned short pw[4][16][72];  // per-wave P transpose staging
  __shared__ float lred[4][4][4];                          // [wave][quad][r] partial denoms
  __shared__ float ored[4][16][64];                        // [wave][row][col] partial O

  const int tid  = threadIdx.x;
  const int wave = tid >> 6;
  const int lane = tid & 63;
  const int l16  = lane & 15;
  const int quad = lane >> 4;

  const int bidx = blockIdx.x;
  const int b    = bidx & 3;
  const int qt   = 255 - (bidx >> 2);

  const unsigned short* Qb = qbf + (size_t)b * SQ * DD;
  const unsigned short* Kb = kbf + (size_t)b * SQ * DD;
  const unsigned short* Vt = vtp + (size_t)b * DD * SQ;  // [D][S]
  float* Wb = out_w  + (size_t)b * SQ * SQ;
  float* Ob = out_vec + (size_t)b * SQ * DD;

  const int q0    = qt * 16;
  const int rowg0 = q0 + quad * 4;           // + r

  bf16x8 aQ0, aQ1;
  {
    const unsigned short* qrow = Qb + (size_t)(q0 + l16) * DD + quad * 8;
    aQ0 = ldfrag(qrow);
    aQ1 = ldfrag(qrow + 32);
  }

  const int nkt = (qt >> 2) + 1;             // causal k-tiles of 64
  const float SC = 0.125f * 1.4426950408889634f;  // 1/sqrt(D) * log2(e)
  const f32x4 zf = {0.f, 0.f, 0.f, 0.f};

  // ---- phase 1: partial softmax denominators over this wave's k-tiles ----
  float lsum[4] = {0.f, 0.f, 0.f, 0.f};
  for (int kt = wave; kt < nkt; kt += 4) {
    const int k0 = kt * 64;
    f32x4 acc[4] = {zf, zf, zf, zf};
#pragma unroll
    for (int ct = 0; ct < 4; ++ct) {
      const unsigned short* krow = Kb + (size_t)(k0 + ct * 16 + l16) * DD + quad * 8;
      bf16x8 b0 = ldfrag(krow);
      bf16x8 b1 = ldfrag(krow + 32);
      acc[ct] = __builtin_amdgcn_mfma_f32_16x16x32_bf16(aQ0, b0, acc[ct], 0, 0, 0);
      acc[ct] = __builtin_amdgcn_mfma_f32_16x16x32_bf16(aQ1, b1, acc[ct], 0, 0, 0);
    }
#pragma unroll
    for (int ct = 0; ct < 4; ++ct) {
      const int colg = k0 + ct * 16 + l16;
#pragma unroll
      for (int r = 0; r < 4; ++r) {
        float tt = (colg <= rowg0 + r) ? acc[ct][r] * SC : -1e30f;
        lsum[r] += __builtin_amdgcn_exp2f(tt);
      }
    }
  }
  // intra-wave reduce over the 16 column-lanes sharing each quad
#pragma unroll
  for (int r = 0; r < 4; ++r) {
    float vsum = lsum[r];
    vsum += __shfl_xor(vsum, 1);
    vsum += __shfl_xor(vsum, 2);
    vsum += __shfl_xor(vsum, 4);
    vsum += __shfl_xor(vsum, 8);
    lsum[r] = vsum;
  }
  if (l16 == 0) {
#pragma unroll
    for (int r = 0; r < 4; ++r) lred[wave][quad][r] = lsum[r];
  }
  __syncthreads();
  float inv_l[4];
#pragma unroll
  for (int r = 0; r < 4; ++r)
    inv_l[r] = 1.0f / (lred[0][quad][r] + lred[1][quad][r] +
                       lred[2][quad][r] + lred[3][quad][r]);

  // ---- phase 2: recompute scores, write P, accumulate partial O = P*V ----
  f32x4 accO[4] = {zf, zf, zf, zf};
  for (int kt = wave; kt < nkt; kt += 4) {
    const int k0 = kt * 64;
    f32x4 acc[4] = {zf, zf, zf, zf};
#pragma unroll
    for (int ct = 0; ct < 4; ++ct) {
      const unsigned short* krow = Kb + (size_t)(k0 + ct * 16 + l16) * DD + quad * 8;
      bf16x8 b0 = ldfrag(krow);
      bf16x8 b1 = ldfrag(krow + 32);
      acc[ct] = __builtin_amdgcn_mfma_f32_16x16x32_bf16(aQ0, b0, acc[ct], 0, 0, 0);
      acc[ct] = __builtin_amdgcn_mfma_f32_16x16x32_bf16(aQ1, b1, acc[ct], 0, 0, 0);
    }
#pragma unroll
    for (int ct = 0; ct < 4; ++ct) {
      const int colg = k0 + ct * 16 + l16;
#pragma unroll
      for (int r = 0; r < 4; ++r) {
        float tt = (colg <= rowg0 + r) ? acc[ct][r] * SC : -1e30f;
        float p  = __builtin_amdgcn_exp2f(tt) * inv_l[r];
        __builtin_nontemporal_store(p, Wb + (size_t)(rowg0 + r) * SQ + colg);
        pw[wave][quad * 4 + r][ct * 16 + l16] = f2bf(p);
      }
    }
    // intra-wave LDS write->read: compiler-inserted lgkmcnt ordering, no barrier
    bf16x8 aP0 = ldfrag(&pw[wave][l16][quad * 8]);
    bf16x8 aP1 = ldfrag(&pw[wave][l16][32 + quad * 8]);
#pragma unroll
    for (int ct = 0; ct < 4; ++ct) {
      const unsigned short* vrow = Vt + (size_t)(ct * 16 + l16) * SQ + k0 + quad * 8;
      bf16x8 b0 = ldfrag(vrow);
      bf16x8 b1 = ldfrag(vrow + 32);
      accO[ct] = __builtin_amdgcn_mfma_f32_16x16x32_bf16(aP0, b0, accO[ct], 0, 0, 0);
      accO[ct] = __builtin_amdgcn_mfma_f32_16x16x32_bf16(aP1, b1, accO[ct], 0, 0, 0);
    }
  }

  // ---- combine partial O across the 4 waves, write attn_vec ----
#pragma unroll
  for (int ct = 0; ct < 4; ++ct)
#pragma unroll
    for (int r = 0; r < 4; ++r)
      ored[wave][quad * 4 + r][ct * 16 + l16] = accO[ct][r];
  __syncthreads();
#pragma unroll
  for (int i = 0; i < 4; ++i) {
    int idx = tid + i * 256;
    int row = idx >> 6, col = idx & 63;
    float s = ored[0][row][col] + ored[1][row][col] +
              ored[2][row][col] + ored[3][row][col];
    Ob[(size_t)(q0 + row) * DD + col] = s;
  }

  // ---- zero-fill fully-masked columns [nkt*64, S) for the 16 rows ----
  const int zc0 = nkt * 64;
  const int nz4 = (SQ - zc0) >> 2;
  if (nz4 > 0) {
    const f32x4 z = {0.f, 0.f, 0.f, 0.f};
    for (int r = 0; r < 16; ++r) {
      f32x4* zp = (f32x4*)(Wb + (size_t)(q0 + r) * SQ + zc0);
      for (int i = tid; i < nz4; i += 256)
        __builtin_nontemporal_store(z, zp + i);
    }
  }
}

extern "C" void kernel_launch(void* const* d_in, const int* in_sizes, int n_in,
                              void* d_out, int out_size, void* d_ws, size_t ws_size,
                              hipStream_t stream) {
  const float* q = (const float*)d_in[0];
  const float* k = (const float*)d_in[1];
  const float* v = (const float*)d_in[2];
  float* out_vec = (float*)d_out;
  float* out_w   = out_vec + (size_t)NB * SQ * DD;
  unsigned short* ws = (unsigned short*)d_ws;  // needs 3*NEL*2 = 6 MB

  hipLaunchKernelGGL(prep_kernel, dim3(1280), dim3(256), 0, stream, q, k, v, ws);
  hipLaunchKernelGGL(attn_kernel, dim3(1024), dim3(256), 0, stream,
                     ws, ws + (size_t)NEL, ws + 2 * (size_t)NEL, out_vec, out_w);
}

// Round 4
// 346.699 us; speedup vs baseline: 1.1233x; 1.0139x over previous
//
#include <hip/hip_runtime.h>

#define SQ 4096
#define DD 64
#define NB 4
#define NEL (NB*SQ*DD)   // 1,048,576 elements per tensor

typedef __attribute__((ext_vector_type(4))) float f32x4;
typedef __attribute__((ext_vector_type(8))) __bf16 bf16x8;

__device__ __forceinline__ unsigned short f2bf(float f) {
  unsigned int u = __builtin_bit_cast(unsigned int, f);
  u = (u + 0x7FFFu + ((u >> 16) & 1u)) >> 16;   // RNE
  return (unsigned short)u;
}

__device__ __forceinline__ bf16x8 ldfrag(const unsigned short* p) {
  uint4 u = *(const uint4*)p;
  return __builtin_bit_cast(bf16x8, u);
}

// pack 8 f32 -> bf16x8 (RNE)
__device__ __forceinline__ bf16x8 pack_bf8(f32x4 a, f32x4 b) {
  union { unsigned short us[8]; bf16x8 v; } u;
  u.us[0] = f2bf(a[0]); u.us[1] = f2bf(a[1]);
  u.us[2] = f2bf(a[2]); u.us[3] = f2bf(a[3]);
  u.us[4] = f2bf(b[0]); u.us[5] = f2bf(b[1]);
  u.us[6] = f2bf(b[2]); u.us[7] = f2bf(b[3]);
  return u.v;
}

// ---------------- prep: Q,K -> bf16 ; V -> bf16 transposed [D][S] ----------------
__global__ __launch_bounds__(256) void prep_kernel(
    const float* __restrict__ q, const float* __restrict__ k,
    const float* __restrict__ v, unsigned short* __restrict__ ws)
{
  unsigned short* qbf = ws;
  unsigned short* kbf = ws + (size_t)NEL;
  unsigned short* vt  = ws + 2*(size_t)NEL;
  const int bid = blockIdx.x;
  const int tid = threadIdx.x;
  if (bid < 1024) {
    const float* src = (bid < 512) ? q : k;
    unsigned short* dst = (bid < 512) ? qbf : kbf;
    const int base = (bid & 511) * 512 + tid;
#pragma unroll
    for (int i = 0; i < 2; ++i) {
      int idx = base + i * 256;
      float4 f = ((const float4*)src)[idx];
      ushort4 o;
      o.x = f2bf(f.x); o.y = f2bf(f.y); o.z = f2bf(f.z); o.w = f2bf(f.w);
      ((ushort4*)dst)[idx] = o;
    }
  } else {
    // transpose V: one block per (batch, 64-row s-tile)
    __shared__ unsigned short tile[64][66];
    const int t  = bid - 1024;
    const int bb = t >> 6;
    const int st = t & 63;
    const float* vb = v + (size_t)bb * SQ * DD + (size_t)st * 64 * DD;
    const int r  = tid >> 4;
    const int c4 = tid & 15;
#pragma unroll
    for (int j = 0; j < 4; ++j) {
      int row = r + j * 16;
      float4 f = ((const float4*)(vb + (size_t)row * DD))[c4];
      tile[row][c4 * 4 + 0] = f2bf(f.x);
      tile[row][c4 * 4 + 1] = f2bf(f.y);
      tile[row][c4 * 4 + 2] = f2bf(f.z);
      tile[row][c4 * 4 + 3] = f2bf(f.w);
    }
    __syncthreads();
    unsigned short* vtb = vt + (size_t)bb * DD * SQ;
#pragma unroll
    for (int j = 0; j < 4; ++j) {
      int d   = r + j * 16;
      int s0l = c4 * 4;
      ushort4 o;
      o.x = tile[s0l + 0][d];
      o.y = tile[s0l + 1][d];
      o.z = tile[s0l + 2][d];
      o.w = tile[s0l + 3][d];
      ((ushort4*)(vtb + (size_t)d * SQ + st * 64))[c4] = o;
    }
  }
}

// ---------------- main fused attention ----------------
// grid: 1024 blocks; b = idx&3, qt = 255 - idx>>2 (heavy q-tiles first, 16 rows each)
// block: 256 threads = 4 waves; waves share the 16 q-rows, k-tiles split wave-
// interleaved. No barriers in k-loops (per-wave LDS staging, intra-wave ordering).
__global__ __launch_bounds__(256, 4) void attn_kernel(
    const unsigned short* __restrict__ qbf,
    const unsigned short* __restrict__ kbf,
    const unsigned short* __restrict__ vtp,
    float* __restrict__ out_vec,
    float* __restrict__ out_w)
{
  // per-wave P f32 staging [16][68]; after the k-loop each wave's region is
  // reused (aliased) as its 16x64 partial-O buffer for the cross-wave combine.
  __shared__ __align__(16) float pt[4][16][68];
  __shared__ float lred[4][4][4];   // [wave][quad][r] partial denominators

  const int tid  = threadIdx.x;
  const int wave = tid >> 6;
  const int lane = tid & 63;
  const int l16  = lane & 15;
  const int quad = lane >> 4;

  const int bidx = blockIdx.x;
  const int b    = bidx & 3;        // XCD x sees only batch x&3 -> K/V L2-resident
  const int qt   = 255 - (bidx >> 2);

  const unsigned short* Qb = qbf + (size_t)b * SQ * DD;
  const unsigned short* Kb = kbf + (size_t)b * SQ * DD;
  const unsigned short* Vt = vtp + (size_t)b * DD * SQ;  // [D][S]
  float* Wb = out_w  + (size_t)b * SQ * SQ;
  float* Ob = out_vec + (size_t)b * SQ * DD;

  const int q0    = qt * 16;
  const int rowg0 = q0 + quad * 4;           // + r

  bf16x8 aQ0, aQ1;
  {
    const unsigned short* qrow = Qb + (size_t)(q0 + l16) * DD + quad * 8;
    aQ0 = ldfrag(qrow);
    aQ1 = ldfrag(qrow + 32);
  }

  const int nkt = (qt >> 2) + 1;             // causal k-tiles of 64
  const float SC = 0.125f * 1.4426950408889634f;  // 1/sqrt(D) * log2(e)
  const f32x4 zf = {0.f, 0.f, 0.f, 0.f};

  // ---- phase 1: partial softmax denominators over this wave's k-tiles ----
  float lsum[4] = {0.f, 0.f, 0.f, 0.f};
  for (int kt = wave; kt < nkt; kt += 4) {
    const int k0 = kt * 64;
    f32x4 acc[4] = {zf, zf, zf, zf};
#pragma unroll
    for (int ct = 0; ct < 4; ++ct) {
      const unsigned short* krow = Kb + (size_t)(k0 + ct * 16 + l16) * DD + quad * 8;
      bf16x8 b0 = ldfrag(krow);
      bf16x8 b1 = ldfrag(krow + 32);
      acc[ct] = __builtin_amdgcn_mfma_f32_16x16x32_bf16(aQ0, b0, acc[ct], 0, 0, 0);
      acc[ct] = __builtin_amdgcn_mfma_f32_16x16x32_bf16(aQ1, b1, acc[ct], 0, 0, 0);
    }
#pragma unroll
    for (int ct = 0; ct < 4; ++ct) {
      const int colg = k0 + ct * 16 + l16;
#pragma unroll
      for (int r = 0; r < 4; ++r) {
        float tt = (colg <= rowg0 + r) ? acc[ct][r] * SC : -1e30f;
        lsum[r] += __builtin_amdgcn_exp2f(tt);
      }
    }
  }
#pragma unroll
  for (int r = 0; r < 4; ++r) {
    float vsum = lsum[r];
    vsum += __shfl_xor(vsum, 1);
    vsum += __shfl_xor(vsum, 2);
    vsum += __shfl_xor(vsum, 4);
    vsum += __shfl_xor(vsum, 8);
    lsum[r] = vsum;
  }
  if (l16 == 0) {
#pragma unroll
    for (int r = 0; r < 4; ++r) lred[wave][quad][r] = lsum[r];
  }
  __syncthreads();
  float inv_l[4];
#pragma unroll
  for (int r = 0; r < 4; ++r)
    inv_l[r] = 1.0f / (lred[0][quad][r] + lred[1][quad][r] +
                       lred[2][quad][r] + lred[3][quad][r]);

  // ---- phase 2: recompute scores, stage P in LDS f32, vector-store P, P*V ----
  f32x4 accO[4] = {zf, zf, zf, zf};
  for (int kt = wave; kt < nkt; kt += 4) {
    const int k0 = kt * 64;
    f32x4 acc[4] = {zf, zf, zf, zf};
#pragma unroll
    for (int ct = 0; ct < 4; ++ct) {
      const unsigned short* krow = Kb + (size_t)(k0 + ct * 16 + l16) * DD + quad * 8;
      bf16x8 b0 = ldfrag(krow);
      bf16x8 b1 = ldfrag(krow + 32);
      acc[ct] = __builtin_amdgcn_mfma_f32_16x16x32_bf16(aQ0, b0, acc[ct], 0, 0, 0);
      acc[ct] = __builtin_amdgcn_mfma_f32_16x16x32_bf16(aQ1, b1, acc[ct], 0, 0, 0);
    }
#pragma unroll
    for (int ct = 0; ct < 4; ++ct) {
      const int colg = k0 + ct * 16 + l16;
#pragma unroll
      for (int r = 0; r < 4; ++r) {
        float tt = (colg <= rowg0 + r) ? acc[ct][r] * SC : -1e30f;
        pt[wave][quad * 4 + r][ct * 16 + l16] = __builtin_amdgcn_exp2f(tt) * inv_l[r];
      }
    }
    // vector store: inst i covers rows 4i..4i+3 x 256B contiguous (full lines)
#pragma unroll
    for (int i = 0; i < 4; ++i) {
      const int rr = 4 * i + quad;
      f32x4 pv = *(const f32x4*)&pt[wave][rr][l16 * 4];
      __builtin_nontemporal_store(pv,
          (f32x4*)(Wb + (size_t)(q0 + rr) * SQ + k0 + l16 * 4));
    }
    // PV: A-fragment of P from the f32 tile, converted in-register
    {
      const float* prow = &pt[wave][l16][0];
      f32x4 p0 = *(const f32x4*)(prow + quad * 8);
      f32x4 p1 = *(const f32x4*)(prow + quad * 8 + 4);
      f32x4 p2 = *(const f32x4*)(prow + 32 + quad * 8);
      f32x4 p3 = *(const f32x4*)(prow + 32 + quad * 8 + 4);
      bf16x8 aP0 = pack_bf8(p0, p1);
      bf16x8 aP1 = pack_bf8(p2, p3);
#pragma unroll
      for (int ct = 0; ct < 4; ++ct) {
        const unsigned short* vrow = Vt + (size_t)(ct * 16 + l16) * SQ + k0 + quad * 8;
        bf16x8 b0 = ldfrag(vrow);
        bf16x8 b1 = ldfrag(vrow + 32);
        accO[ct] = __builtin_amdgcn_mfma_f32_16x16x32_bf16(aP0, b0, accO[ct], 0, 0, 0);
        accO[ct] = __builtin_amdgcn_mfma_f32_16x16x32_bf16(aP1, b1, accO[ct], 0, 0, 0);
      }
    }
  }

  // ---- combine partial O across waves (alias each wave's pt region) ----
  float* ow_mine = &pt[wave][0][0];
#pragma unroll
  for (int ct = 0; ct < 4; ++ct)
#pragma unroll
    for (int r = 0; r < 4; ++r)
      ow_mine[(quad * 4 + r) * 64 + ct * 16 + l16] = accO[ct][r];
  __syncthreads();
#pragma unroll
  for (int i = 0; i < 4; ++i) {
    int idx = tid + i * 256;
    int row = idx >> 6, col = idx & 63;
    float s = pt[0][0][row * 64 + col] + pt[1][0][row * 64 + col] +
              pt[2][0][row * 64 + col] + pt[3][0][row * 64 + col];
    Ob[(size_t)(q0 + row) * DD + col] = s;
  }

  // ---- zero-fill fully-masked columns [nkt*64, S) for the 16 rows ----
  const int zc0 = nkt * 64;
  const int nz4 = (SQ - zc0) >> 2;
  if (nz4 > 0) {
    const f32x4 z = {0.f, 0.f, 0.f, 0.f};
    for (int r = 0; r < 16; ++r) {
      f32x4* zp = (f32x4*)(Wb + (size_t)(q0 + r) * SQ + zc0);
      for (int i = tid; i < nz4; i += 256)
        __builtin_nontemporal_store(z, zp + i);
    }
  }
}

extern "C" void kernel_launch(void* const* d_in, const int* in_sizes, int n_in,
                              void* d_out, int out_size, void* d_ws, size_t ws_size,
                              hipStream_t stream) {
  const float* q = (const float*)d_in[0];
  const float* k = (const float*)d_in[1];
  const float* v = (const float*)d_in[2];
  float* out_vec = (float*)d_out;
  float* out_w   = out_vec + (size_t)NB * SQ * DD;
  unsigned short* ws = (unsigned short*)d_ws;  // needs 3*NEL*2 = 6 MB

  hipLaunchKernelGGL(prep_kernel, dim3(1280), dim3(256), 0, stream, q, k, v, ws);
  hipLaunchKernelGGL(attn_kernel, dim3(1024), dim3(256), 0, stream,
                     ws, ws + (size_t)NEL, ws + 2 * (size_t)NEL, out_vec, out_w);
}